// Round 1
// baseline (295.505 us; speedup 1.0000x reference)
//
#include <hip/hip_runtime.h>
#include <hip/hip_bf16.h>

typedef __attribute__((ext_vector_type(8))) short short8;
typedef __attribute__((ext_vector_type(4))) float float4v;
typedef __attribute__((ext_vector_type(4))) int   int4v;

constexpr int NN = 2048;   // nodes
constexpr int TT = 4;      // time steps
constexpr int HH = 4;      // heads
constexpr int DD = 64;     // head dim
constexpr int THC = TT * HH;
constexpr int NTILE = NN / 64;

__device__ __forceinline__ float bf2f(unsigned short u) {
    union { unsigned int i; float f; } c; c.i = ((unsigned int)u) << 16; return c.f;
}
__device__ __forceinline__ unsigned short f2bf(float f) {
    union { float f; unsigned int i; } c; c.f = f;
    unsigned int x = c.i;
    x += 0x7FFFu + ((x >> 16) & 1u);   // RNE
    return (unsigned short)(x >> 16);
}

// Mask dtype self-detect from first 1 KB (R6/R7-validated; pure fn of d_in).
// 0 = u8/bool, 1 = int32 0/1, 2 = f32, 3 = bf16.
__device__ __forceinline__ int mask_code_of(const unsigned int* mw) {
    int okInt = 1, okF32 = 1, okB = 1, anyLow = 0;
    for (int i = 0; i < 256; i++) {
        unsigned int w = mw[i];
        if (w > 1u) okInt = 0;
        if (!(w == 0u || w == 0x3F800000u)) okF32 = 0;
        unsigned int lo = w & 0xFFFFu, hi = w >> 16;
        if (!((lo == 0u || lo == 0x3F80u) && (hi == 0u || hi == 0x3F80u))) okB = 0;
        if (lo == 0x3F80u) anyLow = 1;
    }
    if (okInt) return 1;
    if (okF32 && !anyLow) return 2;
    if (okB) return 3;
    return 0;
}

// Vectorized raw load of one 16-element mask slice (element base idx), any dtype.
__device__ __forceinline__ void load_mask_raw(const void* p, size_t idx, int code,
                                              int4v mr[4]) {
    if (code == 1) {
        const int4v* mp = (const int4v*)((const int*)p + idx);
        #pragma unroll
        for (int q = 0; q < 4; q++) mr[q] = mp[q];
    } else if (code == 2) {
        const int4v* mp = (const int4v*)((const float*)p + idx);
        #pragma unroll
        for (int q = 0; q < 4; q++) mr[q] = mp[q];
    } else if (code == 3) {
        const int4v* mp = (const int4v*)((const unsigned short*)p + idx);
        mr[0] = mp[0]; mr[1] = mp[1];
    } else {  // u8/bool: 16 consecutive bytes, one dwordx4
        mr[0] = *(const int4v*)((const unsigned char*)p + idx);
    }
}
// Decode raw mask regs -> 16-bit predicate; bit k set iff element k is "true".
// Semantics identical to the old per-element ld_mask() for every code.
__device__ __forceinline__ unsigned decode_pm(const int4v mr[4], int code) {
    unsigned pm = 0u;
    if (code == 1) {
        #pragma unroll
        for (int q = 0; q < 4; q++)
            #pragma unroll
            for (int e = 0; e < 4; e++)
                if (mr[q][e] != 0) pm |= 1u << (q * 4 + e);
    } else if (code == 2) {
        #pragma unroll
        for (int q = 0; q < 4; q++)
            #pragma unroll
            for (int e = 0; e < 4; e++)
                if ((((unsigned)mr[q][e]) << 1) != 0u) pm |= 1u << (q * 4 + e);
    } else if (code == 3) {
        #pragma unroll
        for (int q = 0; q < 2; q++)
            #pragma unroll
            for (int e = 0; e < 4; e++) {
                unsigned w = (unsigned)mr[q][e];
                if (w & 0xFFFFu) pm |= 1u << (q * 8 + e * 2);
                if (w >> 16)     pm |= 1u << (q * 8 + e * 2 + 1);
            }
    } else {
        #pragma unroll
        for (int q = 0; q < 4; q++) {
            unsigned w = (unsigned)mr[0][q];
            #pragma unroll
            for (int b = 0; b < 4; b++)
                if ((w >> (8 * b)) & 0xFFu) pm |= 1u << (q * 4 + b);
        }
    }
    return pm;
}

// ---------------------------------------------------------------------------
// Kernel 1: projections, vectorized — unchanged (R6-validated FMA order).
// ---------------------------------------------------------------------------
constexpr int PROJ_ROWS = 8;
__global__ __launch_bounds__(256) void proj_b16v_kernel(
    const float* __restrict__ x,
    const float* __restrict__ Wq, const float* __restrict__ bq,
    const float* __restrict__ Wk, const float* __restrict__ bk,
    const float* __restrict__ Wv, const float* __restrict__ bv,
    unsigned short* __restrict__ q16, unsigned short* __restrict__ k16,
    unsigned short* __restrict__ v16)
{
    __shared__ float xl[PROJ_ROWS][64];
    const int tid = threadIdx.x;
    const int r0 = blockIdx.x * PROJ_ROWS;
    for (int i = tid; i < PROJ_ROWS * 64; i += 256)
        xl[i >> 6][i & 63] = x[(size_t)r0 * 64 + i];
    __syncthreads();

    const int c = tid;
    const int hh = c >> 6, dd = c & 63;
    const float* Ws[3] = { Wq, Wk, Wv };
    const float* bs[3] = { bq, bk, bv };
    unsigned short* os[3] = { q16, k16, v16 };

    #pragma unroll
    for (int m = 0; m < 3; m++) {
        float4v wr4[16];
        #pragma unroll
        for (int i = 0; i < 16; i++)
            wr4[i] = *(const float4v*)&Ws[m][(size_t)c * 64 + i * 4];
        const float bias = bs[m][c];
        #pragma unroll
        for (int rr = 0; rr < PROJ_ROWS; rr++) {
            float a = bias;
            #pragma unroll
            for (int i = 0; i < 16; i++) {
                a = fmaf(wr4[i][0], xl[rr][4*i+0], a);
                a = fmaf(wr4[i][1], xl[rr][4*i+1], a);
                a = fmaf(wr4[i][2], xl[rr][4*i+2], a);
                a = fmaf(wr4[i][3], xl[rr][4*i+3], a);
            }
            if (m == 0) a *= 0.125f;
            const int r = r0 + rr;
            const int n = r >> 2, t = r & 3;
            const int th = t * HH + hh;
            os[m][((size_t)th * NN + n) * DD + dd] = f2bf(a);
        }
    }
}

// ---------------------------------------------------------------------------
// Kernel 2: MFMA flash attention v3 — SOFTWARE-PIPELINED (T14 async-stage).
// Per iteration: issue tile i+1 K/V->regs + watt->regs + mask->regs (all
// vectorized, all mask dtypes) BEFORE computing tile i; write staged regs to
// LDS after the post-compute barrier. Compute-phase math is byte-identical to
// the R7-validated kernel; mask consumed as a 16-bit predicate (pm).
// mfma_f32_16x16x32_bf16: A lane(row=l&15,k=(l>>4)*8+e),
// B lane(col=l&15,k=(l>>4)*8+e), D lane(col=l&15,row=(l>>4)*4+reg).
// ---------------------------------------------------------------------------
__global__ __launch_bounds__(128, 2) void attn_mfma3_kernel(
    const unsigned short* __restrict__ q16, const unsigned short* __restrict__ k16,
    const unsigned short* __restrict__ v16,
    const float* __restrict__ watt, const void* __restrict__ maskp,
    float* __restrict__ out, float* __restrict__ out_raw)
{
    const int code = mask_code_of((const unsigned int*)maskp);
    const int tid  = threadIdx.x;
    const int wv   = tid >> 6;          // wave 0..1
    const int lane = tid & 63;
    const int g    = lane >> 4;         // MFMA 16-lane group
    const int j0   = lane & 15;
    const int lr   = lane >> 2;         // remap: row 0..15
    const int lc   = lane & 3;          // remap: col quarter 0..3

    const int gid = blockIdx.x;         // 0..1023
    const int th  = ((gid & 7) << 1) | ((gid >> 3) & 1);
    const int bx  = gid >> 4;           // 0..63
    const int t = th >> 2, h = th & 3;
    const int row0 = bx * 32 + wv * 16;

    const unsigned short* Qb = q16 + (size_t)th * NN * DD;
    const unsigned short* Kb = k16 + (size_t)th * NN * DD;
    const unsigned short* Vb = v16 + (size_t)th * NN * DD;

    __shared__ unsigned short Kl[64][80];      // K tile [kv][d], pad 80
    __shared__ unsigned short Vt[64][80];      // V^T tile [d][kv], pad 80
    __shared__ float          Sl[2][16][68];   // per-wave S tile [qrow][kv]
    __shared__ unsigned short Pl[2][16][80];   // per-wave P tile [qrow][kv]

    short8 aq0, aq1;   // Q A-fragments
    {
        const unsigned short* qp = Qb + (size_t)(row0 + j0) * DD + g * 8;
        aq0 = *(const short8*)qp;
        aq1 = *(const short8*)(qp + 32);
    }

    float m_r = -1e30f, l_r = 0.f, m_w = -1e30f, l_w = 0.f;
    float4v o_r[4], o_w[4];
    #pragma unroll
    for (int ns = 0; ns < 4; ns++) {
        o_r[ns] = (float4v){0.f, 0.f, 0.f, 0.f};
        o_w[ns] = (float4v){0.f, 0.f, 0.f, 0.f};
    }

    const size_t mrow = ((size_t)th * NN + row0 + lr) * NN;  // watt/mask row base

    const int kr = tid >> 1;            // staging row 0..63
    const int kc = (tid & 1) << 5;      // staging col half
    const unsigned short* Kp = Kb + (size_t)kr * DD + kc;
    const unsigned short* Vp = Vb + (size_t)kr * DD + kc;

    short8  kreg[4], vreg[4];           // staged next K/V tile
    float4v wcur[4], wnxt[4];           // watt, current / next tile
    int4v   mnxt[4];                    // raw mask, next tile
    unsigned pm;                        // current tile's mask predicate

    // ---------------- prologue: stage tile 0, prefetch its watt/mask -------
    #pragma unroll
    for (int u = 0; u < 4; u++) {
        kreg[u] = ((const short8*)Kp)[u];
        vreg[u] = ((const short8*)Vp)[u];
    }
    {
        const float* wp = watt + mrow + lc * 16;
        #pragma unroll
        for (int q = 0; q < 4; q++) wcur[q] = *(const float4v*)&wp[q * 4];
    }
    load_mask_raw(maskp, mrow + lc * 16, code, mnxt);
    #pragma unroll
    for (int u = 0; u < 4; u++) {
        *(short8*)&Kl[kr][kc + u * 8] = kreg[u];
        #pragma unroll
        for (int e = 0; e < 8; e++)
            Vt[kc + u * 8 + e][kr] = (unsigned short)vreg[u][e];
    }
    __syncthreads();
    pm = decode_pm(mnxt, code);

    for (int it = 0; it < NTILE; ++it) {
        // ---- issue tile it+1 global loads; latency hides under compute ----
        if (it + 1 < NTILE) {
            const size_t kvn = (size_t)(it + 1) * 64;
            const unsigned short* kp = Kp + kvn * DD;
            const unsigned short* vp = Vp + kvn * DD;
            #pragma unroll
            for (int u = 0; u < 4; u++) {
                kreg[u] = ((const short8*)kp)[u];
                vreg[u] = ((const short8*)vp)[u];
            }
            const float* wp = watt + mrow + kvn + lc * 16;
            #pragma unroll
            for (int q = 0; q < 4; q++) wnxt[q] = *(const float4v*)&wp[q * 4];
            load_mask_raw(maskp, mrow + kvn + lc * 16, code, mnxt);
        }

        // ---- QK^T: acc[c][i] = S[row0+4g+i][kv0+16c+j0] ----
        float4v acc[4];
        #pragma unroll
        for (int c = 0; c < 4; c++) {
            short8 b0 = *(const short8*)&Kl[c * 16 + j0][g * 8];
            short8 b1 = *(const short8*)&Kl[c * 16 + j0][32 + g * 8];
            float4v z = (float4v){0.f, 0.f, 0.f, 0.f};
            z = __builtin_amdgcn_mfma_f32_16x16x32_bf16(aq0, b0, z, 0, 0, 0);
            z = __builtin_amdgcn_mfma_f32_16x16x32_bf16(aq1, b1, z, 0, 0, 0);
            acc[c] = z;
        }
        // scatter S to LDS, re-read in remap arrangement (wave-local)
        #pragma unroll
        for (int c = 0; c < 4; c++)
            #pragma unroll
            for (int i = 0; i < 4; i++)
                Sl[wv][g * 4 + i][c * 16 + j0] = acc[c][i];
        float4v s4[4];
        #pragma unroll
        for (int q = 0; q < 4; q++)
            s4[q] = *(const float4v*)&Sl[wv][lr][lc * 16 + q * 4];

        // ---------------- raw path ----------------
        {
            float tmax = -3.0e38f;
            #pragma unroll
            for (int q = 0; q < 4; q++)
                #pragma unroll
                for (int e = 0; e < 4; e++) tmax = fmaxf(tmax, s4[q][e]);
            tmax = fmaxf(tmax, __shfl_xor(tmax, 1, 64));
            tmax = fmaxf(tmax, __shfl_xor(tmax, 2, 64));
            float mn = fmaxf(m_r, tmax);
            float alpha = __expf(m_r - mn);
            m_r = mn;
            alignas(16) unsigned short pb[16];
            float tsum = 0.f;
            #pragma unroll
            for (int q = 0; q < 4; q++)
                #pragma unroll
                for (int e = 0; e < 4; e++) {
                    unsigned short b = f2bf(__expf(s4[q][e] - mn));
                    pb[q * 4 + e] = b; tsum += bf2f(b);
                }
            tsum += __shfl_xor(tsum, 1, 64);
            tsum += __shfl_xor(tsum, 2, 64);
            l_r = l_r * alpha + tsum;
            *(short8*)&Pl[wv][lr][lc * 16]     = *(const short8*)&pb[0];
            *(short8*)&Pl[wv][lr][lc * 16 + 8] = *(const short8*)&pb[8];
            float aR[4];
            #pragma unroll
            for (int i = 0; i < 4; i++) aR[i] = __shfl(alpha, (g * 4 + i) * 4, 64);
            #pragma unroll
            for (int ns = 0; ns < 4; ns++)
                #pragma unroll
                for (int i = 0; i < 4; i++) o_r[ns][i] *= aR[i];
            #pragma unroll
            for (int ks2 = 0; ks2 < 2; ks2++) {
                short8 pa = *(const short8*)&Pl[wv][j0][ks2 * 32 + g * 8];
                #pragma unroll
                for (int ns = 0; ns < 4; ns++) {
                    short8 vb8 = *(const short8*)&Vt[ns * 16 + j0][ks2 * 32 + g * 8];
                    o_r[ns] = __builtin_amdgcn_mfma_f32_16x16x32_bf16(pa, vb8, o_r[ns], 0, 0, 0);
                }
            }
        }

        // ---------------- weighted + masked path ----------------
        {
            float sw[16];
            #pragma unroll
            for (int q = 0; q < 4; q++)
                #pragma unroll
                for (int e = 0; e < 4; e++) {
                    const int k = q * 4 + e;
                    sw[k] = ((pm >> k) & 1u) ? -1e30f : s4[q][e] * wcur[q][e];
                }
            float tmax = -3.0e38f;
            #pragma unroll
            for (int k = 0; k < 16; k++) tmax = fmaxf(tmax, sw[k]);
            tmax = fmaxf(tmax, __shfl_xor(tmax, 1, 64));
            tmax = fmaxf(tmax, __shfl_xor(tmax, 2, 64));
            float mn = fmaxf(m_w, tmax);
            float alpha = __expf(m_w - mn);
            m_w = mn;
            alignas(16) unsigned short pb[16];
            float tsum = 0.f;
            #pragma unroll
            for (int k = 0; k < 16; k++) {
                unsigned short b = f2bf(__expf(sw[k] - mn));
                pb[k] = b; tsum += bf2f(b);
            }
            tsum += __shfl_xor(tsum, 1, 64);
            tsum += __shfl_xor(tsum, 2, 64);
            l_w = l_w * alpha + tsum;
            *(short8*)&Pl[wv][lr][lc * 16]     = *(const short8*)&pb[0];
            *(short8*)&Pl[wv][lr][lc * 16 + 8] = *(const short8*)&pb[8];
            float aW[4];
            #pragma unroll
            for (int i = 0; i < 4; i++) aW[i] = __shfl(alpha, (g * 4 + i) * 4, 64);
            #pragma unroll
            for (int ns = 0; ns < 4; ns++)
                #pragma unroll
                for (int i = 0; i < 4; i++) o_w[ns][i] *= aW[i];
            #pragma unroll
            for (int ks2 = 0; ks2 < 2; ks2++) {
                short8 pa = *(const short8*)&Pl[wv][j0][ks2 * 32 + g * 8];
                #pragma unroll
                for (int ns = 0; ns < 4; ns++) {
                    short8 vb8 = *(const short8*)&Vt[ns * 16 + j0][ks2 * 32 + g * 8];
                    o_w[ns] = __builtin_amdgcn_mfma_f32_16x16x32_bf16(pa, vb8, o_w[ns], 0, 0, 0);
                }
            }
        }

        // ---- write-late: commit tile it+1 staging, rotate prefetch regs ---
        __syncthreads();
        if (it + 1 < NTILE) {
            #pragma unroll
            for (int u = 0; u < 4; u++) {
                *(short8*)&Kl[kr][kc + u * 8] = kreg[u];
                #pragma unroll
                for (int e = 0; e < 8; e++)
                    Vt[kc + u * 8 + e][kr] = (unsigned short)vreg[u][e];
            }
            #pragma unroll
            for (int q = 0; q < 4; q++) wcur[q] = wnxt[q];
            pm = decode_pm(mnxt, code);
        }
        __syncthreads();
    }

    // epilogue: pull per-row l via shfl, normalize, store f32 (H,N,T,D)
    float lR[4], lW[4];
    #pragma unroll
    for (int i = 0; i < 4; i++) {
        lR[i] = __shfl(l_r, (g * 4 + i) * 4, 64);
        lW[i] = __shfl(l_w, (g * 4 + i) * 4, 64);
    }
    #pragma unroll
    for (int i = 0; i < 4; i++) {
        const int row = row0 + g * 4 + i;
        const size_t ob = (((size_t)h * NN + row) * TT + t) * DD;
        const float ir = 1.0f / lR[i];
        const float iw = 1.0f / lW[i];
        #pragma unroll
        for (int ns = 0; ns < 4; ns++) {
            out[ob + ns * 16 + j0]     = o_w[ns][i] * iw;
            out_raw[ob + ns * 16 + j0] = o_r[ns][i] * ir;
        }
    }
}

// ---------------------------------------------------------------------------
// Kernel 3: raw_att[t=3,h=0] slice — unchanged (R7-validated).
// ---------------------------------------------------------------------------
__global__ __launch_bounds__(256) void slice_b16_kernel(
    const unsigned short* __restrict__ q16, const unsigned short* __restrict__ k16,
    float* __restrict__ out_sl)
{
    const int tid = threadIdx.x;
    const int w = tid >> 6, lane = tid & 63;
    const int thsel = 12;  // t=3, h=0
    const unsigned short* Kb = k16 + (size_t)thsel * NN * DD;

    __shared__ float Tt[64][65];
    __shared__ float sr[4][NN];
    __shared__ float ql[4][64];

    ql[tid >> 6][tid & 63] =
        bf2f(q16[((size_t)thsel * NN + blockIdx.x * 4 + (tid >> 6))* DD + (tid & 63)]);
    __syncthreads();
    float qr[64];
    #pragma unroll
    for (int d = 0; d < 64; d++) qr[d] = ql[w][d];

    for (int kt = 0; kt < NN / 64; ++kt) {
        __syncthreads();
        const unsigned short* Ks = Kb + (size_t)kt * 64 * DD;
        #pragma unroll
        for (int u = 0; u < 16; ++u) {
            int e = u * 256 + tid;
            Tt[e >> 6][e & 63] = bf2f(Ks[e]);
        }
        __syncthreads();
        float a = 0.f;
        #pragma unroll
        for (int d = 0; d < 64; ++d)
            a = fmaf(qr[d], Tt[lane][d], a);
        sr[w][kt * 64 + lane] = a;
    }

    const int r = blockIdx.x * 4 + w;
    float mx = -3.0e38f;
    for (int m = lane; m < NN; m += 64) mx = fmaxf(mx, sr[w][m]);
    #pragma unroll
    for (int o = 1; o < 64; o <<= 1) mx = fmaxf(mx, __shfl_xor(mx, o, 64));
    float se = 0.f;
    for (int m = lane; m < NN; m += 64) se += __expf(sr[w][m] - mx);
    #pragma unroll
    for (int o = 1; o < 64; o <<= 1) se += __shfl_xor(se, o, 64);
    const float inv = 1.0f / se;
    for (int m = lane; m < NN; m += 64)
        out_sl[(size_t)r * NN + m] = __expf(sr[w][m] - mx) * inv;
}

// ---------------------------------------------------------------------------
extern "C" void kernel_launch(void* const* d_in, const int* in_sizes, int n_in,
                              void* d_out, int out_size, void* d_ws, size_t ws_size,
                              hipStream_t stream)
{
    (void)in_sizes; (void)n_in; (void)out_size; (void)ws_size;
    const float* x    = (const float*)d_in[0];
    const float* Wq   = (const float*)d_in[1];
    const float* bq   = (const float*)d_in[2];
    const float* Wk   = (const float*)d_in[3];
    const float* bk   = (const float*)d_in[4];
    const float* Wv   = (const float*)d_in[5];
    const float* bv   = (const float*)d_in[6];
    const float* watt = (const float*)d_in[7];
    const void*  mask = d_in[8];

    unsigned short* q16 = (unsigned short*)d_ws;              // 4 MB
    unsigned short* k16 = q16 + (size_t)THC * NN * DD;        // +4 MB
    unsigned short* v16 = k16 + (size_t)THC * NN * DD;        // +4 MB (12 MB)

    float* out     = (float*)d_out;
    float* out_raw = out + (size_t)NN * TT * HH * DD;
    float* out_sl  = out + 2 * (size_t)NN * TT * HH * DD;

    proj_b16v_kernel<<<NN * TT / PROJ_ROWS, 256, 0, stream>>>(
        x, Wq, bq, Wk, bk, Wv, bv, q16, k16, v16);
    attn_mfma3_kernel<<<(NN / 32) * THC, 128, 0, stream>>>(
        q16, k16, v16, watt, mask, out, out_raw);
    slice_b16_kernel<<<NN / 4, 256, 0, stream>>>(q16, k16, out_sl);
}